// Round 8
// baseline (689.278 us; speedup 1.0000x reference)
//
#include <hip/hip_runtime.h>
#include <hip/hip_bf16.h>

#define TT 2048
#define BB 8
#define HH 8
#define NNS 32
#define MM (BB * TT)
#define CH 16   // scan chunk rows staged in LDS

typedef __attribute__((ext_vector_type(8))) short short8;
typedef __attribute__((ext_vector_type(4))) float f32x4;

__device__ __forceinline__ float bf2f(ushort u) {
    return __uint_as_float(((unsigned)u) << 16);
}
__device__ __forceinline__ ushort f2bf(float f) {
    unsigned x = __float_as_uint(f);
    unsigned r = (x + 0x7fffu + ((x >> 16) & 1u)) >> 16;
    return (ushort)r;
}
__device__ __forceinline__ float sigmoidf_fast(float x) {
    float e = __builtin_amdgcn_exp2f(x * -1.4426950408889634f);
    return __builtin_amdgcn_rcpf(1.0f + e);
}
__device__ __forceinline__ float tanhf_fast(float x) {
    // 1 - 2/(e^{2x}+1); exp2 over/underflow saturates to +-1, no clamp needed
    float e = __builtin_amdgcn_exp2f(x * 2.8853900817779268f);
    return fmaf(-2.0f, __builtin_amdgcn_rcpf(e + 1.0f), 1.0f);
}

// async global->LDS, 16B per lane. Dest must be wave-uniform base + lane*16.
__device__ __forceinline__ void gl16(const void* g, void* l) {
    auto gp = (const __attribute__((address_space(1))) unsigned int*)g;
    auto lp = (__attribute__((address_space(3))) unsigned int*)l;
    __builtin_amdgcn_global_load_lds(gp, lp, 16, 0, 0);
}

template<int CTRL>
__device__ __forceinline__ float dpp_add(float x) {
    int y = __builtin_amdgcn_update_dpp(0, __float_as_int(x), CTRL, 0xF, 0xF, true);
    return x + __int_as_float(y);
}
// 16-lane rotate-reduce: every lane of each 16-lane row ends with the row sum.
__device__ __forceinline__ float red16(float x) {
    x = dpp_add<0xB1>(x);    // quad_perm xor1
    x = dpp_add<0x4E>(x);    // quad_perm xor2
    x = dpp_add<0x124>(x);   // row_ror:4
    x = dpp_add<0x128>(x);   // row_ror:8
    return x;
}

__device__ __forceinline__ void split8(const float4& x0, const float4& x1,
                                       ushort* __restrict__ h, ushort* __restrict__ l) {
    float xs[8] = {x0.x, x0.y, x0.z, x0.w, x1.x, x1.y, x1.z, x1.w};
#pragma unroll
    for (int i = 0; i < 8; ++i) {
        ushort hh = f2bf(xs[i]);
        h[i] = hh;
        l[i] = f2bf(xs[i] - bf2f(hh));
    }
}

// ---------------- conversion pre-passes (memory-bound) ----------------
__global__ __launch_bounds__(256) void conv_x_kernel(
    const float* __restrict__ src, ushort* __restrict__ hi, ushort* __restrict__ lo)
{
    size_t e = ((size_t)blockIdx.x * 256 + threadIdx.x) * 8;
    float4 x0 = *reinterpret_cast<const float4*>(src + e);
    float4 x1 = *reinterpret_cast<const float4*>(src + e + 4);
    ushort h[8], l[8];
    split8(x0, x1, h, l);
    *reinterpret_cast<uint4*>(hi + e) = *reinterpret_cast<const uint4*>(h);
    *reinterpret_cast<uint4*>(lo + e) = *reinterpret_cast<const uint4*>(l);
}

// all weights -> planes. [0,1M) W_in -> W1h/W1l; [1M,2M) concat(Wk,Wv,Wq,Wb)
// -> W2h/W2l; [2M,2.25M) W_out -> W3h (hi only).
__global__ __launch_bounds__(256) void conv_w_kernel(
    const float* __restrict__ Wi, const float* __restrict__ Wk,
    const float* __restrict__ Wv, const float* __restrict__ Wq,
    const float* __restrict__ Wb, const float* __restrict__ Wo,
    ushort* __restrict__ W1h, ushort* __restrict__ W1l,
    ushort* __restrict__ W2h, ushort* __restrict__ W2l,
    ushort* __restrict__ W3h)
{
    size_t e = ((size_t)blockIdx.x * 256 + threadIdx.x) * 8;
    const float* s;
    ushort* dh; ushort* dl; size_t doff; bool dolo = true;
    if (e < 1048576) {
        s = Wi + e; dh = W1h; dl = W1l; doff = e;
    } else if (e < 2097152) {
        size_t u = e - 1048576;
        int wi = (int)(u >> 18);
        const float* sp = (wi == 0) ? Wk : (wi == 1) ? Wv : (wi == 2) ? Wq : Wb;
        s = sp + (u & 262143); dh = W2h; dl = W2l; doff = u;
    } else {
        size_t u = e - 2097152;
        s = Wo + u; dh = W3h; dl = nullptr; doff = u; dolo = false;
    }
    float4 x0 = *reinterpret_cast<const float4*>(s);
    float4 x1 = *reinterpret_cast<const float4*>(s + 4);
    ushort h[8], l[8];
    split8(x0, x1, h, l);
    *reinterpret_cast<uint4*>(dh + doff) = *reinterpret_cast<const uint4*>(h);
    if (dolo)
        *reinterpret_cast<uint4*>(dl + doff) = *reinterpret_cast<const uint4*>(l);
}

// ---------------- 128x128-tile split GEMM, global_load_lds staging ----------
template<int ACT>
__global__ __launch_bounds__(256, 3) void gemm_planes(
    const ushort* __restrict__ Ah_g, const ushort* __restrict__ Al_g,
    const ushort* __restrict__ Wh_g, const ushort* __restrict__ Wl_g,
    const float* __restrict__ bbeta,
    ushort* __restrict__ Ch, ushort* __restrict__ Cl,
    float* __restrict__ Cf, int M, int N, int K)
{
    __shared__ __align__(16) ushort sAh[128][32], sAl[128][32];
    __shared__ __align__(16) ushort sWh[128][32], sWl[128][32];
    const int t = threadIdx.x;
    const int wave = t >> 6, lane = t & 63;
    const int lr = lane & 15, lq = lane >> 4;
    const int wm = wave >> 1, wn = wave & 1;

    // XCD-aware bijective swizzle (nwg=1024, 1024%8==0)
    const int bid = blockIdx.y * 8 + blockIdx.x;
    const int swz = (bid & 7) * 128 + (bid >> 3);
    const int n0 = (swz & 7) * 128;
    const int m0 = (swz >> 3) * 128;

    const int rs0 = wave * 32 + (lane >> 2);
    const int rs1 = rs0 + 16;
    const int ce  = (lane & 3) * 8;
    const ushort* gA0h = Ah_g + (size_t)(m0 + rs0) * K + ce;
    const ushort* gA1h = Ah_g + (size_t)(m0 + rs1) * K + ce;
    const ushort* gA0l = Al_g + (size_t)(m0 + rs0) * K + ce;
    const ushort* gA1l = Al_g + (size_t)(m0 + rs1) * K + ce;
    const ushort* gW0h = Wh_g + (size_t)(n0 + rs0) * K + ce;
    const ushort* gW1h = Wh_g + (size_t)(n0 + rs1) * K + ce;
    const ushort* gW0l = Wl_g + (size_t)(n0 + rs0) * K + ce;
    const ushort* gW1l = Wl_g + (size_t)(n0 + rs1) * K + ce;
    const int lb = wave * 2048 + lane * 16;
    char* LAh = (char*)&sAh[0][0];
    char* LAl = (char*)&sAl[0][0];
    char* LWh = (char*)&sWh[0][0];
    char* LWl = (char*)&sWl[0][0];

    f32x4 acc[4][4];
#pragma unroll
    for (int mi = 0; mi < 4; ++mi)
#pragma unroll
        for (int ni = 0; ni < 4; ++ni) acc[mi][ni] = (f32x4){0.f, 0.f, 0.f, 0.f};

    const int NK = K >> 5;
    for (int ks = 0; ks < NK; ++ks) {
        const int k0 = ks << 5;
        __syncthreads();   // prior reads of LDS done -> safe to overwrite
        gl16(gA0h + k0, LAh + lb);  gl16(gA1h + k0, LAh + lb + 1024);
        gl16(gA0l + k0, LAl + lb);  gl16(gA1l + k0, LAl + lb + 1024);
        gl16(gW0h + k0, LWh + lb);  gl16(gW1h + k0, LWh + lb + 1024);
        gl16(gW0l + k0, LWl + lb);  gl16(gW1l + k0, LWl + lb + 1024);
        __syncthreads();   // compiler drains vmcnt(0): staged data visible
        short8 ah[4], al[4], wh[4], wl[4];
#pragma unroll
        for (int mi = 0; mi < 4; ++mi) {
            ah[mi] = *reinterpret_cast<const short8*>(&sAh[wm * 64 + mi * 16 + lr][lq * 8]);
            al[mi] = *reinterpret_cast<const short8*>(&sAl[wm * 64 + mi * 16 + lr][lq * 8]);
        }
#pragma unroll
        for (int ni = 0; ni < 4; ++ni) {
            wh[ni] = *reinterpret_cast<const short8*>(&sWh[wn * 64 + ni * 16 + lr][lq * 8]);
            wl[ni] = *reinterpret_cast<const short8*>(&sWl[wn * 64 + ni * 16 + lr][lq * 8]);
        }
#pragma unroll
        for (int mi = 0; mi < 4; ++mi) {
#pragma unroll
            for (int ni = 0; ni < 4; ++ni) {
                acc[mi][ni] = __builtin_amdgcn_mfma_f32_16x16x32_bf16(ah[mi], wh[ni], acc[mi][ni], 0, 0, 0);
                acc[mi][ni] = __builtin_amdgcn_mfma_f32_16x16x32_bf16(ah[mi], wl[ni], acc[mi][ni], 0, 0, 0);
                acc[mi][ni] = __builtin_amdgcn_mfma_f32_16x16x32_bf16(al[mi], wh[ni], acc[mi][ni], 0, 0, 0);
            }
        }
    }

#pragma unroll
    for (int mi = 0; mi < 4; ++mi) {
#pragma unroll
        for (int ni = 0; ni < 4; ++ni) {
#pragma unroll
            for (int r2 = 0; r2 < 4; ++r2) {
                int mg = m0 + wm * 64 + mi * 16 + lq * 4 + r2;
                int ng = n0 + wn * 64 + ni * 16 + lr;
                float v = acc[mi][ni][r2];
                if (ACT == 1) {
                    v = v * sigmoidf_fast(v);
                    ushort h = f2bf(v);
                    ushort lo_ = f2bf(v - bf2f(h));
                    Ch[(size_t)mg * N + ng] = h;
                    Cl[(size_t)mg * N + ng] = lo_;
                } else {
                    if (ACT == 2 && ng >= 768) v = sigmoidf_fast(v + bbeta[ng - 768]);
                    Cf[(size_t)mg * N + ng] = v;
                }
            }
        }
    }
}

// GEMM3: A = cell bf16, W = pre-converted hi plane. Same gload_lds structure.
__global__ __launch_bounds__(256, 4) void gemm_cell(
    const ushort* __restrict__ A, const ushort* __restrict__ Wh_g,
    float* __restrict__ C, int M, int N, int K)
{
    __shared__ __align__(16) ushort sA[128][32];
    __shared__ __align__(16) ushort sW[128][32];
    const int t = threadIdx.x;
    const int wave = t >> 6, lane = t & 63;
    const int lr = lane & 15, lq = lane >> 4;
    const int wm = wave >> 1, wn = wave & 1;

    const int bid = blockIdx.y * 8 + blockIdx.x;
    const int swz = (bid & 7) * 128 + (bid >> 3);
    const int n0 = (swz & 7) * 128;
    const int m0 = (swz >> 3) * 128;

    const int rs0 = wave * 32 + (lane >> 2);
    const int rs1 = rs0 + 16;
    const int ce  = (lane & 3) * 8;
    const ushort* gA0 = A    + (size_t)(m0 + rs0) * K + ce;
    const ushort* gA1 = A    + (size_t)(m0 + rs1) * K + ce;
    const ushort* gW0 = Wh_g + (size_t)(n0 + rs0) * K + ce;
    const ushort* gW1 = Wh_g + (size_t)(n0 + rs1) * K + ce;
    const int lb = wave * 2048 + lane * 16;
    char* LA = (char*)&sA[0][0];
    char* LW = (char*)&sW[0][0];

    f32x4 acc[4][4];
#pragma unroll
    for (int mi = 0; mi < 4; ++mi)
#pragma unroll
        for (int ni = 0; ni < 4; ++ni) acc[mi][ni] = (f32x4){0.f, 0.f, 0.f, 0.f};

    const int NK = K >> 5;
    for (int ks = 0; ks < NK; ++ks) {
        const int k0 = ks << 5;
        __syncthreads();
        gl16(gA0 + k0, LA + lb);  gl16(gA1 + k0, LA + lb + 1024);
        gl16(gW0 + k0, LW + lb);  gl16(gW1 + k0, LW + lb + 1024);
        __syncthreads();
        short8 af[4], wf[4];
#pragma unroll
        for (int mi = 0; mi < 4; ++mi)
            af[mi] = *reinterpret_cast<const short8*>(&sA[wm * 64 + mi * 16 + lr][lq * 8]);
#pragma unroll
        for (int ni = 0; ni < 4; ++ni)
            wf[ni] = *reinterpret_cast<const short8*>(&sW[wn * 64 + ni * 16 + lr][lq * 8]);
#pragma unroll
        for (int mi = 0; mi < 4; ++mi)
#pragma unroll
            for (int ni = 0; ni < 4; ++ni)
                acc[mi][ni] = __builtin_amdgcn_mfma_f32_16x16x32_bf16(af[mi], wf[ni], acc[mi][ni], 0, 0, 0);
    }

#pragma unroll
    for (int mi = 0; mi < 4; ++mi) {
#pragma unroll
        for (int ni = 0; ni < 4; ++ni) {
#pragma unroll
            for (int r2 = 0; r2 < 4; ++r2) {
                int mg = m0 + wm * 64 + mi * 16 + lq * 4 + r2;
                int ng = n0 + wn * 64 + ni * 16 + lr;
                C[(size_t)mg * N + ng] = acc[mi][ni][r2];
            }
        }
    }
}

// kn precompute: kn[b,t,h,j] = k / (||k||_h + 1e-6). Parallel over all (b,t,h).
__global__ __launch_bounds__(256) void kn_kernel(
    const float* __restrict__ P, float* __restrict__ KN)
{
    int idx = blockIdx.x * 256 + threadIdx.x;    // over MM*256
    int col = idx & 255;                          // h*32 + j
    int bt  = idx >> 8;
    float k = P[(size_t)bt * 1024 + col];
    float ks = k * k;
    ks += __shfl_xor(ks, 1, 32);  ks += __shfl_xor(ks, 2, 32);
    ks += __shfl_xor(ks, 4, 32);  ks += __shfl_xor(ks, 8, 32);
    ks += __shfl_xor(ks, 16, 32);
    KN[idx] = k * __builtin_amdgcn_rcpf(sqrtf(ks) + 1e-6f);
}

// ---------------- scan: dual-chain interleave + LDS chunk staging ----------
// KEY STRUCTURE: rows of S evolve independently (p_i, delta_i, row update
// depend only on row i + the shared kn_t). Each 64-thread wave now carries
// TWO row-sets (X: rows qp*4+iw, Y: rows qp*4+iw+16) of the same (b,h).
// Their per-step computations are mutually independent -> X's VALU ops fill
// Y's dependency-chain stalls and vice versa (the single-wave serial chain
// was the 241cy/step bottleneck; memory was already staged). kn/q LDS data
// and staging are shared between the chains; 256 blocks (1/CU).
__device__ __forceinline__ void lds_load8d(
    float (&K_)[CH][32], float (&Q_)[CH][32], float (&VB)[CH][16],
    int base, int l, int iw,
    float (&k0)[8], float (&k1)[8], float (&q0)[8], float (&q1)[8],
    float (&vx)[8], float (&bx)[8], float (&vy)[8], float (&by)[8])
{
#pragma unroll
    for (int u = 0; u < 8; ++u) {
        k0[u] = K_[base + u][l];  k1[u] = K_[base + u][l + 16];
        q0[u] = Q_[base + u][l];  q1[u] = Q_[base + u][l + 16];
        vx[u] = VB[base + u][iw];      vy[u] = VB[base + u][4 + iw];
        bx[u] = VB[base + u][8 + iw];  by[u] = VB[base + u][12 + iw];
    }
}

__device__ __forceinline__ void steps8d(
    float (&k0)[8], float (&k1)[8], float (&q0)[8], float (&q1)[8],
    float (&vx)[8], float (&bx)[8], float (&vy)[8], float (&by)[8],
    float& SX0, float& SX1, float& SY0, float& SY1,
    float (&sqx)[8], float (&sqy)[8])
{
#pragma unroll
    for (int u = 0; u < 8; ++u) {
        // two independent chains: X ops fill Y's stall slots and vice versa
        float px = red16(fmaf(SX0, k0[u], SX1 * k1[u]));
        float py = red16(fmaf(SY0, k0[u], SY1 * k1[u]));
        float dx = vx[u] - px;
        float dy = vy[u] - py;
        SX0 = tanhf_fast(fmaf(bx[u], SX0, dx * k0[u]));
        SX1 = tanhf_fast(fmaf(bx[u], SX1, dx * k1[u]));
        SY0 = tanhf_fast(fmaf(by[u], SY0, dy * k0[u]));
        SY1 = tanhf_fast(fmaf(by[u], SY1, dy * k1[u]));
        sqx[u] = fmaf(SX0, q0[u], SX1 * q1[u]);
        sqy[u] = fmaf(SY0, q0[u], SY1 * q1[u]);
    }
}

__device__ __forceinline__ void flush8(
    float (&sqp)[8], ushort* __restrict__ cell, size_t crow, int l)
{
    // 8 independent reduces: pipeline, issue-bound not latency-bound
    float r0 = red16(sqp[0]), r1 = red16(sqp[1]);
    float r2 = red16(sqp[2]), r3 = red16(sqp[3]);
    float r4 = red16(sqp[4]), r5 = red16(sqp[5]);
    float r6 = red16(sqp[6]), r7 = red16(sqp[7]);
    if (l < 8) {
        float s01 = (l & 1) ? r1 : r0;
        float s23 = (l & 1) ? r3 : r2;
        float s45 = (l & 1) ? r5 : r4;
        float s67 = (l & 1) ? r7 : r6;
        float a03 = (l & 2) ? s23 : s01;
        float a47 = (l & 2) ? s67 : s45;
        float sel = (l & 4) ? a47 : a03;
        float o = sel * sel * sigmoidf_fast(sel);    // Sq * silu(Sq)
        cell[crow + (size_t)l * 256] = f2bf(o);
    }
}

template<int DO_STAGE>
__device__ __forceinline__ void scan_chunk16d(
    float (&K_)[CH][32], float (&Q_)[CH][32], float (&VB)[CH][16],
    float (&NK)[CH][32], float (&NQ)[CH][32], float (&NVB)[CH][16],
    const float*& gkn, const float*& gq,
    const float*& gvx, const float*& gvy, const float*& gbx, const float*& gby,
    float (&k0A)[8], float (&k1A)[8], float (&q0A)[8], float (&q1A)[8],
    float (&vxA)[8], float (&bxA)[8], float (&vyA)[8], float (&byA)[8],
    float (&k0B)[8], float (&k1B)[8], float (&q0B)[8], float (&q1B)[8],
    float (&vxB)[8], float (&bxB)[8], float (&vyB)[8], float (&byB)[8],
    float& SX0, float& SX1, float& SY0, float& SY1,
    float (&sqx)[8], float (&sqy)[8],
    ushort* __restrict__ cell, size_t crowX, size_t crowY, int l, int iw, int j)
{
    float4 Lk0, Lk1, Lq0, Lq1;
    float Lvx = 0.f, Lvy = 0.f, Lbx = 0.f, Lby = 0.f;
    if (DO_STAGE) {
        // issue-early: latency hides under the 16 steps below
        Lk0 = *reinterpret_cast<const float4*>(gkn);
        Lk1 = *reinterpret_cast<const float4*>(gkn + 8 * 256);
        Lq0 = *reinterpret_cast<const float4*>(gq);
        Lq1 = *reinterpret_cast<const float4*>(gq + 8 * 1024);
        Lvx = *gvx;  Lvy = *gvy;  Lbx = *gbx;  Lby = *gby;
        gkn += CH * 256; gq += CH * 1024;
        gvx += CH * 1024; gvy += CH * 1024; gbx += CH * 1024; gby += CH * 1024;
    }
    // batch-read rows 8-15 of CURRENT chunk into regB (used after steps 0-7)
    lds_load8d(K_, Q_, VB, 8, l, iw, k0B, k1B, q0B, q1B, vxB, bxB, vyB, byB);
    // steps 0-7 from regA (pure VALU, two interleaved chains)
    steps8d(k0A, k1A, q0A, q1A, vxA, bxA, vyA, byA, SX0, SX1, SY0, SY1, sqx, sqy);
    flush8(sqx, cell, crowX, l);
    flush8(sqy, cell, crowY, l);
    if (DO_STAGE) {
        // write-late: globals had 8 steps to land
        *reinterpret_cast<float4*>(&NK[j >> 3][(j & 7) * 4]) = Lk0;
        *reinterpret_cast<float4*>(&NK[8 + (j >> 3)][(j & 7) * 4]) = Lk1;
        *reinterpret_cast<float4*>(&NQ[j >> 3][(j & 7) * 4]) = Lq0;
        *reinterpret_cast<float4*>(&NQ[8 + (j >> 3)][(j & 7) * 4]) = Lq1;
        NVB[j >> 2][j & 3]        = Lvx;
        NVB[j >> 2][4 + (j & 3)]  = Lvy;
        NVB[j >> 2][8 + (j & 3)]  = Lbx;
        NVB[j >> 2][12 + (j & 3)] = Lby;
        // batch-read next chunk's rows 0-7 into regA (used after steps 8-15)
        lds_load8d(NK, NQ, NVB, 0, l, iw, k0A, k1A, q0A, q1A, vxA, bxA, vyA, byA);
    }
    // steps 8-15 from regB
    steps8d(k0B, k1B, q0B, q1B, vxB, bxB, vyB, byB, SX0, SX1, SY0, SY1, sqx, sqy);
    flush8(sqx, cell, crowX + (size_t)8 * 256, l);
    flush8(sqy, cell, crowY + (size_t)8 * 256, l);
}

__global__ __launch_bounds__(64, 1) void scan_kernel(
    const float* __restrict__ P,
    const float* __restrict__ KN,
    ushort* __restrict__ cell,     // [B*T, 256] bf16
    float* __restrict__ Sout)      // [B,H,32,32] fp32
{
    const int b  = blockIdx.x & 7;       // XCD-local batch slice
    const int r  = blockIdx.x >> 3;      // 0..31
    const int h  = r & 7;
    const int qp = r >> 3;               // 0..3
    const int j  = threadIdx.x;
    const int l  = j & 15;
    const int iw = j >> 4;               // 0..3
    const int iX = qp * 4 + iw;          // chain X row (0..15)
    const int iY = iX + 16;              // chain Y row (16..31)

    __shared__ __align__(16) float sK0[CH][32], sK1[CH][32];
    __shared__ __align__(16) float sQ0[CH][32], sQ1[CH][32];
    __shared__ __align__(16) float sVB0[CH][16], sVB1[CH][16];

    const size_t bt0 = (size_t)b * TT;
    // per-lane coalesced source cursors (point at next chunk to stage)
    const float* gkn = KN + (bt0 + (j >> 3)) * 256 + h * 32 + (j & 7) * 4;
    const float* gq  = P  + (bt0 + (j >> 3)) * 1024 + 512 + h * 32 + (j & 7) * 4;
    const float* gvx = P  + (bt0 + (j >> 2)) * 1024 + 256 + h * 32 + qp * 4 + (j & 3);
    const float* gvy = gvx + 16;
    const float* gbx = P  + (bt0 + (j >> 2)) * 1024 + 768 + h * 32 + qp * 4 + (j & 3);
    const float* gby = gbx + 16;

    float k0A[8], k1A[8], q0A[8], q1A[8], vxA[8], bxA[8], vyA[8], byA[8];
    float k0B[8], k1B[8], q0B[8], q1B[8], vxB[8], bxB[8], vyB[8], byB[8];
    float sqx[8], sqy[8];
    float SX0 = 0.f, SX1 = 0.f, SY0 = 0.f, SY1 = 0.f;
    const size_t cbX = (size_t)b * TT * 256 + h * 32 + iX;
    const size_t cbY = cbX + 16;

    // prologue: stage chunk 0 into buf0, batch-read its rows 0-7 into regA
    {
        float4 K0v = *reinterpret_cast<const float4*>(gkn);
        float4 K1v = *reinterpret_cast<const float4*>(gkn + 8 * 256);
        float4 Q0v = *reinterpret_cast<const float4*>(gq);
        float4 Q1v = *reinterpret_cast<const float4*>(gq + 8 * 1024);
        float vx0 = *gvx, vy0 = *gvy, bx0 = *gbx, by0 = *gby;
        gkn += CH * 256; gq += CH * 1024;
        gvx += CH * 1024; gvy += CH * 1024; gbx += CH * 1024; gby += CH * 1024;
        *reinterpret_cast<float4*>(&sK0[j >> 3][(j & 7) * 4]) = K0v;
        *reinterpret_cast<float4*>(&sK0[8 + (j >> 3)][(j & 7) * 4]) = K1v;
        *reinterpret_cast<float4*>(&sQ0[j >> 3][(j & 7) * 4]) = Q0v;
        *reinterpret_cast<float4*>(&sQ0[8 + (j >> 3)][(j & 7) * 4]) = Q1v;
        sVB0[j >> 2][j & 3]        = vx0;
        sVB0[j >> 2][4 + (j & 3)]  = vy0;
        sVB0[j >> 2][8 + (j & 3)]  = bx0;
        sVB0[j >> 2][12 + (j & 3)] = by0;
    }
    lds_load8d(sK0, sQ0, sVB0, 0, l, iw, k0A, k1A, q0A, q1A, vxA, bxA, vyA, byA);

    size_t crowX = cbX, crowY = cbY;
    for (int c = 0; c < 63; ++c) {
        scan_chunk16d<1>(sK0, sQ0, sVB0, sK1, sQ1, sVB1,
                         gkn, gq, gvx, gvy, gbx, gby,
                         k0A, k1A, q0A, q1A, vxA, bxA, vyA, byA,
                         k0B, k1B, q0B, q1B, vxB, bxB, vyB, byB,
                         SX0, SX1, SY0, SY1, sqx, sqy,
                         cell, crowX, crowY, l, iw, j);
        crowX += (size_t)CH * 256;  crowY += (size_t)CH * 256;
        scan_chunk16d<1>(sK1, sQ1, sVB1, sK0, sQ0, sVB0,
                         gkn, gq, gvx, gvy, gbx, gby,
                         k0A, k1A, q0A, q1A, vxA, bxA, vyA, byA,
                         k0B, k1B, q0B, q1B, vxB, bxB, vyB, byB,
                         SX0, SX1, SY0, SY1, sqx, sqy,
                         cell, crowX, crowY, l, iw, j);
        crowX += (size_t)CH * 256;  crowY += (size_t)CH * 256;
    }
    // chunk 126 (buf0), stages chunk 127 -> buf1 and preloads its rows 0-7
    scan_chunk16d<1>(sK0, sQ0, sVB0, sK1, sQ1, sVB1,
                     gkn, gq, gvx, gvy, gbx, gby,
                     k0A, k1A, q0A, q1A, vxA, bxA, vyA, byA,
                     k0B, k1B, q0B, q1B, vxB, bxB, vyB, byB,
                     SX0, SX1, SY0, SY1, sqx, sqy,
                     cell, crowX, crowY, l, iw, j);
    crowX += (size_t)CH * 256;  crowY += (size_t)CH * 256;
    // chunk 127 (buf1), no staging
    scan_chunk16d<0>(sK1, sQ1, sVB1, sK0, sQ0, sVB0,
                     gkn, gq, gvx, gvy, gbx, gby,
                     k0A, k1A, q0A, q1A, vxA, bxA, vyA, byA,
                     k0B, k1B, q0B, q1B, vxB, bxB, vyB, byB,
                     SX0, SX1, SY0, SY1, sqx, sqy,
                     cell, crowX, crowY, l, iw, j);

    float* soX = Sout + (((size_t)(b * HH + h)) * NNS + iX) * NNS;
    soX[l] = SX0;
    soX[l + 16] = SX1;
    float* soY = Sout + (((size_t)(b * HH + h)) * NNS + iY) * NNS;
    soY[l] = SY0;
    soY[l + 16] = SY1;
}

extern "C" void kernel_launch(void* const* d_in, const int* in_sizes, int n_in,
                              void* d_out, int out_size, void* d_ws, size_t ws_size,
                              hipStream_t stream) {
    const float* x     = (const float*)d_in[0];
    const float* W_in  = (const float*)d_in[1];
    const float* W_k   = (const float*)d_in[2];
    const float* W_v   = (const float*)d_in[3];
    const float* W_q   = (const float*)d_in[4];
    const float* W_b   = (const float*)d_in[5];
    const float* b_b   = (const float*)d_in[6];
    const float* W_out = (const float*)d_in[7];
    float* out = (float*)d_out;

    const int M = MM;                                    // 16384
    float* f = (float*)d_ws;
    // region A: P fp32 [M,1024] — ALIASES Xh/Xl (dead before gemm2 writes P)
    float*  P    = f;
    ushort* Xh   = (ushort*)f;
    ushort* Xl   = Xh + (size_t)M * 1024;
    // region B: xp hi/lo planes [M,1024] each
    ushort* xpH  = (ushort*)(f + (size_t)M * 1024);
    ushort* xpL  = xpH + (size_t)M * 1024;
    // region C/D
    float*  KN   = f + (size_t)2 * M * 1024;             // M*256 fp32
    ushort* cell = (ushort*)(KN + (size_t)M * 256);      // M*256 bf16
    ushort* wb   = cell + (size_t)M * 256;               // weight planes
    ushort* W1h = wb;                    // 1M
    ushort* W1l = W1h + 1048576;         // 1M
    ushort* W2h = W1l + 1048576;         // 1M
    ushort* W2l = W2h + 1048576;         // 1M
    ushort* W3h = W2l + 1048576;         // 256K

    dim3 blk(256);
    dim3 g1(1024 / 128, M / 128);

    // 0) conversions (memory-bound pre-passes)
    conv_x_kernel<<<dim3((M * 1024) / (8 * 256)), blk, 0, stream>>>(x, Xh, Xl);
    conv_w_kernel<<<dim3(2359296 / (8 * 256)), blk, 0, stream>>>(
        W_in, W_k, W_v, W_q, W_b, W_out, W1h, W1l, W2h, W2l, W3h);
    // 1) xp = silu(x @ W_in^T), written directly as hi/lo planes
    gemm_planes<1><<<g1, blk, 0, stream>>>(Xh, Xl, W1h, W1l, b_b,
                                           xpH, xpL, nullptr, M, 1024, 1024);
    // 2) P = xp @ [Wk;Wv;Wq;Wbeta]^T, beta block: sigmoid(. + b_beta)
    gemm_planes<2><<<g1, blk, 0, stream>>>(xpH, xpL, W2h, W2l, b_b,
                                           nullptr, nullptr, P, M, 1024, 1024);
    // 3) kn = k / (||k|| + 1e-6)
    kn_kernel<<<dim3((M * 256) / 256), blk, 0, stream>>>(P, KN);
    // 4) recurrent scan -> cell (bf16) + S_final (fp32, d_out tail)
    //    dual-chain: 256 blocks (1/CU), each wave runs rows i and i+16
    scan_kernel<<<dim3(256), dim3(64), 0, stream>>>(P, KN, cell, out + (size_t)M * 1024);
    // 5) y = cell @ W_out^T
    gemm_cell<<<g1, blk, 0, stream>>>(cell, W3h, out, M, 1024, 256);
}

// Round 10
// 572.837 us; speedup vs baseline: 1.2033x; 1.2033x over previous
//
#include <hip/hip_runtime.h>
#include <hip/hip_bf16.h>

#define TT 2048
#define BB 8
#define HH 8
#define NNS 32
#define MM (BB * TT)
#define CH 16   // scan chunk rows staged in LDS
#define TANHC 2.8853900817779268f   // 2*log2(e)

typedef __attribute__((ext_vector_type(8))) short short8;
typedef __attribute__((ext_vector_type(4))) float f32x4;

__device__ __forceinline__ float bf2f(ushort u) {
    return __uint_as_float(((unsigned)u) << 16);
}
__device__ __forceinline__ ushort f2bf(float f) {
    unsigned x = __float_as_uint(f);
    unsigned r = (x + 0x7fffu + ((x >> 16) & 1u)) >> 16;
    return (ushort)r;
}
__device__ __forceinline__ float sigmoidf_fast(float x) {
    float e = __builtin_amdgcn_exp2f(x * -1.4426950408889634f);
    return __builtin_amdgcn_rcpf(1.0f + e);
}

// async global->LDS, 16B per lane. Dest must be wave-uniform base + lane*16.
__device__ __forceinline__ void gl16(const void* g, void* l) {
    auto gp = (const __attribute__((address_space(1))) unsigned int*)g;
    auto lp = (__attribute__((address_space(3))) unsigned int*)l;
    __builtin_amdgcn_global_load_lds(gp, lp, 16, 0, 0);
}

// 16-lane rotate-reduce via builtin update_dpp: the compiler's DPP-combine
// pass fuses mov_dpp+add into v_add_f32_dpp where legal AND handles the
// VALU->DPP hazard wait-states (r9 lesson: hand-written asm DPP chains get
// no hazard mitigation -> silent wrong-lane reads).
template<int CTRL>
__device__ __forceinline__ float dpp_add(float x) {
    int y = __builtin_amdgcn_update_dpp(0, __float_as_int(x), CTRL, 0xF, 0xF, true);
    return x + __int_as_float(y);
}
__device__ __forceinline__ float red16(float x) {
    x = dpp_add<0xB1>(x);    // quad_perm xor1
    x = dpp_add<0x4E>(x);    // quad_perm xor2
    x = dpp_add<0x124>(x);   // row_ror:4
    x = dpp_add<0x128>(x);   // row_ror:8
    return x;
}

__device__ __forceinline__ void split8(const float4& x0, const float4& x1,
                                       ushort* __restrict__ h, ushort* __restrict__ l) {
    float xs[8] = {x0.x, x0.y, x0.z, x0.w, x1.x, x1.y, x1.z, x1.w};
#pragma unroll
    for (int i = 0; i < 8; ++i) {
        ushort hh = f2bf(xs[i]);
        h[i] = hh;
        l[i] = f2bf(xs[i] - bf2f(hh));
    }
}

// ---------------- conversion pre-passes (memory-bound) ----------------
__global__ __launch_bounds__(256) void conv_x_kernel(
    const float* __restrict__ src, ushort* __restrict__ hi, ushort* __restrict__ lo)
{
    size_t e = ((size_t)blockIdx.x * 256 + threadIdx.x) * 8;
    float4 x0 = *reinterpret_cast<const float4*>(src + e);
    float4 x1 = *reinterpret_cast<const float4*>(src + e + 4);
    ushort h[8], l[8];
    split8(x0, x1, h, l);
    *reinterpret_cast<uint4*>(hi + e) = *reinterpret_cast<const uint4*>(h);
    *reinterpret_cast<uint4*>(lo + e) = *reinterpret_cast<const uint4*>(l);
}

// all weights -> planes. [0,1M) W_in -> W1h/W1l; [1M,2M) concat(Wk,Wv,Wq,Wb)
// -> W2h/W2l; [2M,2.25M) W_out -> W3h (hi only).
__global__ __launch_bounds__(256) void conv_w_kernel(
    const float* __restrict__ Wi, const float* __restrict__ Wk,
    const float* __restrict__ Wv, const float* __restrict__ Wq,
    const float* __restrict__ Wb, const float* __restrict__ Wo,
    ushort* __restrict__ W1h, ushort* __restrict__ W1l,
    ushort* __restrict__ W2h, ushort* __restrict__ W2l,
    ushort* __restrict__ W3h)
{
    size_t e = ((size_t)blockIdx.x * 256 + threadIdx.x) * 8;
    const float* s;
    ushort* dh; ushort* dl; size_t doff; bool dolo = true;
    if (e < 1048576) {
        s = Wi + e; dh = W1h; dl = W1l; doff = e;
    } else if (e < 2097152) {
        size_t u = e - 1048576;
        int wi = (int)(u >> 18);
        const float* sp = (wi == 0) ? Wk : (wi == 1) ? Wv : (wi == 2) ? Wq : Wb;
        s = sp + (u & 262143); dh = W2h; dl = W2l; doff = u;
    } else {
        size_t u = e - 2097152;
        s = Wo + u; dh = W3h; dl = nullptr; doff = u; dolo = false;
    }
    float4 x0 = *reinterpret_cast<const float4*>(s);
    float4 x1 = *reinterpret_cast<const float4*>(s + 4);
    ushort h[8], l[8];
    split8(x0, x1, h, l);
    *reinterpret_cast<uint4*>(dh + doff) = *reinterpret_cast<const uint4*>(h);
    if (dolo)
        *reinterpret_cast<uint4*>(dl + doff) = *reinterpret_cast<const uint4*>(l);
}

// ---------------- 128x128-tile split GEMM, global_load_lds staging ----------
template<int ACT>
__global__ __launch_bounds__(256, 3) void gemm_planes(
    const ushort* __restrict__ Ah_g, const ushort* __restrict__ Al_g,
    const ushort* __restrict__ Wh_g, const ushort* __restrict__ Wl_g,
    const float* __restrict__ bbeta,
    ushort* __restrict__ Ch, ushort* __restrict__ Cl,
    float* __restrict__ Cf, int M, int N, int K)
{
    __shared__ __align__(16) ushort sAh[128][32], sAl[128][32];
    __shared__ __align__(16) ushort sWh[128][32], sWl[128][32];
    const int t = threadIdx.x;
    const int wave = t >> 6, lane = t & 63;
    const int lr = lane & 15, lq = lane >> 4;
    const int wm = wave >> 1, wn = wave & 1;

    // XCD-aware bijective swizzle (nwg=1024, 1024%8==0)
    const int bid = blockIdx.y * 8 + blockIdx.x;
    const int swz = (bid & 7) * 128 + (bid >> 3);
    const int n0 = (swz & 7) * 128;
    const int m0 = (swz >> 3) * 128;

    const int rs0 = wave * 32 + (lane >> 2);
    const int rs1 = rs0 + 16;
    const int ce  = (lane & 3) * 8;
    const ushort* gA0h = Ah_g + (size_t)(m0 + rs0) * K + ce;
    const ushort* gA1h = Ah_g + (size_t)(m0 + rs1) * K + ce;
    const ushort* gA0l = Al_g + (size_t)(m0 + rs0) * K + ce;
    const ushort* gA1l = Al_g + (size_t)(m0 + rs1) * K + ce;
    const ushort* gW0h = Wh_g + (size_t)(n0 + rs0) * K + ce;
    const ushort* gW1h = Wh_g + (size_t)(n0 + rs1) * K + ce;
    const ushort* gW0l = Wl_g + (size_t)(n0 + rs0) * K + ce;
    const ushort* gW1l = Wl_g + (size_t)(n0 + rs1) * K + ce;
    const int lb = wave * 2048 + lane * 16;
    char* LAh = (char*)&sAh[0][0];
    char* LAl = (char*)&sAl[0][0];
    char* LWh = (char*)&sWh[0][0];
    char* LWl = (char*)&sWl[0][0];

    f32x4 acc[4][4];
#pragma unroll
    for (int mi = 0; mi < 4; ++mi)
#pragma unroll
        for (int ni = 0; ni < 4; ++ni) acc[mi][ni] = (f32x4){0.f, 0.f, 0.f, 0.f};

    const int NK = K >> 5;
    for (int ks = 0; ks < NK; ++ks) {
        const int k0 = ks << 5;
        __syncthreads();   // prior reads of LDS done -> safe to overwrite
        gl16(gA0h + k0, LAh + lb);  gl16(gA1h + k0, LAh + lb + 1024);
        gl16(gA0l + k0, LAl + lb);  gl16(gA1l + k0, LAl + lb + 1024);
        gl16(gW0h + k0, LWh + lb);  gl16(gW1h + k0, LWh + lb + 1024);
        gl16(gW0l + k0, LWl + lb);  gl16(gW1l + k0, LWl + lb + 1024);
        __syncthreads();   // compiler drains vmcnt(0): staged data visible
        short8 ah[4], al[4], wh[4], wl[4];
#pragma unroll
        for (int mi = 0; mi < 4; ++mi) {
            ah[mi] = *reinterpret_cast<const short8*>(&sAh[wm * 64 + mi * 16 + lr][lq * 8]);
            al[mi] = *reinterpret_cast<const short8*>(&sAl[wm * 64 + mi * 16 + lr][lq * 8]);
        }
#pragma unroll
        for (int ni = 0; ni < 4; ++ni) {
            wh[ni] = *reinterpret_cast<const short8*>(&sWh[wn * 64 + ni * 16 + lr][lq * 8]);
            wl[ni] = *reinterpret_cast<const short8*>(&sWl[wn * 64 + ni * 16 + lr][lq * 8]);
        }
#pragma unroll
        for (int mi = 0; mi < 4; ++mi) {
#pragma unroll
            for (int ni = 0; ni < 4; ++ni) {
                acc[mi][ni] = __builtin_amdgcn_mfma_f32_16x16x32_bf16(ah[mi], wh[ni], acc[mi][ni], 0, 0, 0);
                acc[mi][ni] = __builtin_amdgcn_mfma_f32_16x16x32_bf16(ah[mi], wl[ni], acc[mi][ni], 0, 0, 0);
                acc[mi][ni] = __builtin_amdgcn_mfma_f32_16x16x32_bf16(al[mi], wh[ni], acc[mi][ni], 0, 0, 0);
            }
        }
    }

#pragma unroll
    for (int mi = 0; mi < 4; ++mi) {
#pragma unroll
        for (int ni = 0; ni < 4; ++ni) {
#pragma unroll
            for (int r2 = 0; r2 < 4; ++r2) {
                int mg = m0 + wm * 64 + mi * 16 + lq * 4 + r2;
                int ng = n0 + wn * 64 + ni * 16 + lr;
                float v = acc[mi][ni][r2];
                if (ACT == 1) {
                    v = v * sigmoidf_fast(v);
                    ushort h = f2bf(v);
                    ushort lo_ = f2bf(v - bf2f(h));
                    Ch[(size_t)mg * N + ng] = h;
                    Cl[(size_t)mg * N + ng] = lo_;
                } else {
                    if (ACT == 2 && ng >= 768) v = sigmoidf_fast(v + bbeta[ng - 768]);
                    Cf[(size_t)mg * N + ng] = v;
                }
            }
        }
    }
}

// GEMM3: A = cell bf16, W = pre-converted hi plane. Same gload_lds structure.
__global__ __launch_bounds__(256, 4) void gemm_cell(
    const ushort* __restrict__ A, const ushort* __restrict__ Wh_g,
    float* __restrict__ C, int M, int N, int K)
{
    __shared__ __align__(16) ushort sA[128][32];
    __shared__ __align__(16) ushort sW[128][32];
    const int t = threadIdx.x;
    const int wave = t >> 6, lane = t & 63;
    const int lr = lane & 15, lq = lane >> 4;
    const int wm = wave >> 1, wn = wave & 1;

    const int bid = blockIdx.y * 8 + blockIdx.x;
    const int swz = (bid & 7) * 128 + (bid >> 3);
    const int n0 = (swz & 7) * 128;
    const int m0 = (swz >> 3) * 128;

    const int rs0 = wave * 32 + (lane >> 2);
    const int rs1 = rs0 + 16;
    const int ce  = (lane & 3) * 8;
    const ushort* gA0 = A    + (size_t)(m0 + rs0) * K + ce;
    const ushort* gA1 = A    + (size_t)(m0 + rs1) * K + ce;
    const ushort* gW0 = Wh_g + (size_t)(n0 + rs0) * K + ce;
    const ushort* gW1 = Wh_g + (size_t)(n0 + rs1) * K + ce;
    const int lb = wave * 2048 + lane * 16;
    char* LA = (char*)&sA[0][0];
    char* LW = (char*)&sW[0][0];

    f32x4 acc[4][4];
#pragma unroll
    for (int mi = 0; mi < 4; ++mi)
#pragma unroll
        for (int ni = 0; ni < 4; ++ni) acc[mi][ni] = (f32x4){0.f, 0.f, 0.f, 0.f};

    const int NK = K >> 5;
    for (int ks = 0; ks < NK; ++ks) {
        const int k0 = ks << 5;
        __syncthreads();
        gl16(gA0 + k0, LA + lb);  gl16(gA1 + k0, LA + lb + 1024);
        gl16(gW0 + k0, LW + lb);  gl16(gW1 + k0, LW + lb + 1024);
        __syncthreads();
        short8 af[4], wf[4];
#pragma unroll
        for (int mi = 0; mi < 4; ++mi)
            af[mi] = *reinterpret_cast<const short8*>(&sA[wm * 64 + mi * 16 + lr][lq * 8]);
#pragma unroll
        for (int ni = 0; ni < 4; ++ni)
            wf[ni] = *reinterpret_cast<const short8*>(&sW[wn * 64 + ni * 16 + lr][lq * 8]);
#pragma unroll
        for (int mi = 0; mi < 4; ++mi)
#pragma unroll
            for (int ni = 0; ni < 4; ++ni)
                acc[mi][ni] = __builtin_amdgcn_mfma_f32_16x16x32_bf16(af[mi], wf[ni], acc[mi][ni], 0, 0, 0);
    }

#pragma unroll
    for (int mi = 0; mi < 4; ++mi) {
#pragma unroll
        for (int ni = 0; ni < 4; ++ni) {
#pragma unroll
            for (int r2 = 0; r2 < 4; ++r2) {
                int mg = m0 + wm * 64 + mi * 16 + lq * 4 + r2;
                int ng = n0 + wn * 64 + ni * 16 + lr;
                C[(size_t)mg * N + ng] = acc[mi][ni][r2];
            }
        }
    }
}

// kn precompute: kn[b,t,h,j] = k / (||k||_h + 1e-6). Parallel over all (b,t,h).
__global__ __launch_bounds__(256) void kn_kernel(
    const float* __restrict__ P, float* __restrict__ KN)
{
    int idx = blockIdx.x * 256 + threadIdx.x;    // over MM*256
    int col = idx & 255;                          // h*32 + j
    int bt  = idx >> 8;
    float k = P[(size_t)bt * 1024 + col];
    float ks = k * k;
    ks += __shfl_xor(ks, 1, 32);  ks += __shfl_xor(ks, 2, 32);
    ks += __shfl_xor(ks, 4, 32);  ks += __shfl_xor(ks, 8, 32);
    ks += __shfl_xor(ks, 16, 32);
    KN[idx] = k * __builtin_amdgcn_rcpf(sqrtf(ks) + 1e-6f);
}

// ---------------- scan: LDS chunk-staged, chain-shortened steps ----------
// Chain shortened via algebraic re-association (exact math, only rounding
// differs): c*(b*S+(v-p)*k) = [bc*S + v*kc] - p*kc; the bracket depends only
// on S -> computed in parallel with the p-reduce; kc/bc prescaled off-chain.
// Post-reduce chain: fma -> exp2 -> add -> rcp -> fma (was sub,mul,fma,mul,
// exp2,add,rcp,fma). red16 stays builtin-DPP (r9 lesson).
__device__ __forceinline__ void lds_load8(
    float (&K_)[CH][32], float (&Q_)[CH][32], float (&VB)[CH][8],
    int base, int l, int iw,
    float (&k0)[8], float (&k1)[8], float (&q0)[8], float (&q1)[8],
    float (&vv)[8], float (&k0c)[8], float (&k1c)[8], float (&bc)[8])
{
#pragma unroll
    for (int u = 0; u < 8; ++u) {
        k0[u] = K_[base + u][l];  k1[u] = K_[base + u][l + 16];
        q0[u] = Q_[base + u][l];  q1[u] = Q_[base + u][l + 16];
        vv[u] = VB[base + u][iw];
        float b = VB[base + u][iw + 4];
        k0c[u] = k0[u] * TANHC;
        k1c[u] = k1[u] * TANHC;
        bc[u]  = b * TANHC;
    }
}

__device__ __forceinline__ void steps8(
    float (&k0)[8], float (&k1)[8], float (&q0)[8], float (&q1)[8],
    float (&vv)[8], float (&k0c)[8], float (&k1c)[8], float (&bc)[8],
    float& S0, float& S1, float (&sqp)[8])
{
#pragma unroll
    for (int u = 0; u < 8; ++u) {
        // off-chain of the reduce (dep only on S): bracket = bc*S + v*kc
        float u0 = fmaf(vv[u], k0c[u], bc[u] * S0);
        float u1 = fmaf(vv[u], k1c[u], bc[u] * S1);
        // critical chain: mul+fma -> 4 DPP adds -> fma -> exp2 -> add -> rcp -> fma
        float p = red16(fmaf(S0, k0[u], S1 * k1[u]));
        float e0 = __builtin_amdgcn_exp2f(fmaf(-p, k0c[u], u0));
        float e1 = __builtin_amdgcn_exp2f(fmaf(-p, k1c[u], u1));
        S0 = fmaf(-2.0f, __builtin_amdgcn_rcpf(e0 + 1.0f), 1.0f);
        S1 = fmaf(-2.0f, __builtin_amdgcn_rcpf(e1 + 1.0f), 1.0f);
        // off-chain: 2-op partial only; reduce deferred to flush8
        sqp[u] = fmaf(S0, q0[u], S1 * q1[u]);
    }
}

__device__ __forceinline__ void flush8(
    float (&sqp)[8], ushort* __restrict__ cell, size_t crow, int l)
{
    // 8 independent reduces: pipeline, issue-bound not latency-bound
    float r0 = red16(sqp[0]), r1 = red16(sqp[1]);
    float r2 = red16(sqp[2]), r3 = red16(sqp[3]);
    float r4 = red16(sqp[4]), r5 = red16(sqp[5]);
    float r6 = red16(sqp[6]), r7 = red16(sqp[7]);
    if (l < 8) {
        float s01 = (l & 1) ? r1 : r0;
        float s23 = (l & 1) ? r3 : r2;
        float s45 = (l & 1) ? r5 : r4;
        float s67 = (l & 1) ? r7 : r6;
        float a03 = (l & 2) ? s23 : s01;
        float a47 = (l & 2) ? s67 : s45;
        float sel = (l & 4) ? a47 : a03;
        float o = sel * sel * sigmoidf_fast(sel);    // Sq * silu(Sq)
        cell[crow + (size_t)l * 256] = f2bf(o);
    }
}

template<int DO_STAGE>
__device__ __forceinline__ void scan_chunk16(
    float (&K_)[CH][32], float (&Q_)[CH][32], float (&VB)[CH][8],
    float (&NK)[CH][32], float (&NQ)[CH][32], float (&NVB)[CH][8],
    const float*& gkn, const float*& gq, const float*& gv, const float*& gb,
    float (&k0A)[8], float (&k1A)[8], float (&q0A)[8], float (&q1A)[8],
    float (&vvA)[8], float (&k0cA)[8], float (&k1cA)[8], float (&bcA)[8],
    float (&k0B)[8], float (&k1B)[8], float (&q0B)[8], float (&q1B)[8],
    float (&vvB)[8], float (&k0cB)[8], float (&k1cB)[8], float (&bcB)[8],
    float& S0, float& S1, float (&sqp)[8],
    ushort* __restrict__ cell, size_t crow, int l, int iw, int j)
{
    float4 Lk0, Lk1, Lq0, Lq1;
    float Lv = 0.f, Lb = 0.f;
    if (DO_STAGE) {
        // issue-early: latency hides under the 16 steps below
        Lk0 = *reinterpret_cast<const float4*>(gkn);
        Lk1 = *reinterpret_cast<const float4*>(gkn + 8 * 256);
        Lq0 = *reinterpret_cast<const float4*>(gq);
        Lq1 = *reinterpret_cast<const float4*>(gq + 8 * 1024);
        Lv  = *gv;
        Lb  = *gb;
        gkn += CH * 256; gq += CH * 1024; gv += CH * 1024; gb += CH * 1024;
    }
    // batch-read rows 8-15 of CURRENT chunk into regB (used after steps 0-7)
    lds_load8(K_, Q_, VB, 8, l, iw, k0B, k1B, q0B, q1B, vvB, k0cB, k1cB, bcB);
    // steps 0-7 from regA (no memory ops on the serial path)
    steps8(k0A, k1A, q0A, q1A, vvA, k0cA, k1cA, bcA, S0, S1, sqp);
    flush8(sqp, cell, crow, l);
    if (DO_STAGE) {
        // write-late: globals had 8 steps to land
        *reinterpret_cast<float4*>(&NK[j >> 3][(j & 7) * 4]) = Lk0;
        *reinterpret_cast<float4*>(&NK[8 + (j >> 3)][(j & 7) * 4]) = Lk1;
        *reinterpret_cast<float4*>(&NQ[j >> 3][(j & 7) * 4]) = Lq0;
        *reinterpret_cast<float4*>(&NQ[8 + (j >> 3)][(j & 7) * 4]) = Lq1;
        NVB[j >> 2][j & 3] = Lv;
        NVB[j >> 2][4 + (j & 3)] = Lb;
        // batch-read next chunk's rows 0-7 into regA (used after steps 8-15)
        lds_load8(NK, NQ, NVB, 0, l, iw, k0A, k1A, q0A, q1A, vvA, k0cA, k1cA, bcA);
    }
    // steps 8-15 from regB
    steps8(k0B, k1B, q0B, q1B, vvB, k0cB, k1cB, bcB, S0, S1, sqp);
    flush8(sqp, cell, crow + (size_t)8 * 256, l);
}

__global__ __launch_bounds__(64, 1) void scan_kernel(
    const float* __restrict__ P,
    const float* __restrict__ KN,
    ushort* __restrict__ cell,     // [B*T, 256] bf16
    float* __restrict__ Sout)      // [B,H,32,32] fp32
{
    const int b    = blockIdx.x & 7;     // XCD-local batch slice
    const int r    = blockIdx.x >> 3;    // 0..63
    const int h    = r & 7;
    const int quad = r >> 3;             // 0..7
    const int j    = threadIdx.x;
    const int l    = j & 15;
    const int iw   = j >> 4;             // 0..3
    const int i    = quad * 4 + iw;

    __shared__ __align__(16) float sK0[CH][32], sK1[CH][32];
    __shared__ __align__(16) float sQ0[CH][32], sQ1[CH][32];
    __shared__ __align__(16) float sVB0[CH][8], sVB1[CH][8];

    const size_t bt0 = (size_t)b * TT;
    // per-lane coalesced source cursors (point at next chunk to stage)
    const float* gkn = KN + (bt0 + (j >> 3)) * 256 + h * 32 + (j & 7) * 4;
    const float* gq  = P  + (bt0 + (j >> 3)) * 1024 + 512 + h * 32 + (j & 7) * 4;
    const float* gv  = P  + (bt0 + (j >> 2)) * 1024 + 256 + h * 32 + quad * 4 + (j & 3);
    const float* gb  = P  + (bt0 + (j >> 2)) * 1024 + 768 + h * 32 + quad * 4 + (j & 3);

    float k0A[8], k1A[8], q0A[8], q1A[8], vvA[8], k0cA[8], k1cA[8], bcA[8];
    float k0B[8], k1B[8], q0B[8], q1B[8], vvB[8], k0cB[8], k1cB[8], bcB[8];
    float sqp[8];
    float S0 = 0.f, S1 = 0.f;
    const size_t cb = (size_t)b * TT * 256 + h * 32 + i;

    // prologue: stage chunk 0 into buf0, batch-read its rows 0-7 into regA
    {
        float4 K0v = *reinterpret_cast<const float4*>(gkn);
        float4 K1v = *reinterpret_cast<const float4*>(gkn + 8 * 256);
        float4 Q0v = *reinterpret_cast<const float4*>(gq);
        float4 Q1v = *reinterpret_cast<const float4*>(gq + 8 * 1024);
        float v0 = *gv, b0 = *gb;
        gkn += CH * 256; gq += CH * 1024; gv += CH * 1024; gb += CH * 1024;
        *reinterpret_cast<float4*>(&sK0[j >> 3][(j & 7) * 4]) = K0v;
        *reinterpret_cast<float4*>(&sK0[8 + (j >> 3)][(j & 7) * 4]) = K1v;
        *reinterpret_cast<float4*>(&sQ0[j >> 3][(j & 7) * 4]) = Q0v;
        *reinterpret_cast<float4*>(&sQ0[8 + (j >> 3)][(j & 7) * 4]) = Q1v;
        sVB0[j >> 2][j & 3] = v0;
        sVB0[j >> 2][4 + (j & 3)] = b0;
    }
    lds_load8(sK0, sQ0, sVB0, 0, l, iw, k0A, k1A, q0A, q1A, vvA, k0cA, k1cA, bcA);

    size_t crow = cb;
    for (int c = 0; c < 63; ++c) {
        scan_chunk16<1>(sK0, sQ0, sVB0, sK1, sQ1, sVB1,
                        gkn, gq, gv, gb,
                        k0A, k1A, q0A, q1A, vvA, k0cA, k1cA, bcA,
                        k0B, k1B, q0B, q1B, vvB, k0cB, k1cB, bcB,
                        S0, S1, sqp, cell, crow, l, iw, j);
        crow += (size_t)CH * 256;
        scan_chunk16<1>(sK1, sQ1, sVB1, sK0, sQ0, sVB0,
                        gkn, gq, gv, gb,
                        k0A, k1A, q0A, q1A, vvA, k0cA, k1cA, bcA,
                        k0B, k1B, q0B, q1B, vvB, k0cB, k1cB, bcB,
                        S0, S1, sqp, cell, crow, l, iw, j);
        crow += (size_t)CH * 256;
    }
    // chunk 126 (buf0), stages chunk 127 -> buf1 and preloads its rows 0-7
    scan_chunk16<1>(sK0, sQ0, sVB0, sK1, sQ1, sVB1,
                    gkn, gq, gv, gb,
                    k0A, k1A, q0A, q1A, vvA, k0cA, k1cA, bcA,
                    k0B, k1B, q0B, q1B, vvB, k0cB, k1cB, bcB,
                    S0, S1, sqp, cell, crow, l, iw, j);
    crow += (size_t)CH * 256;
    // chunk 127 (buf1), no staging
    scan_chunk16<0>(sK1, sQ1, sVB1, sK0, sQ0, sVB0,
                    gkn, gq, gv, gb,
                    k0A, k1A, q0A, q1A, vvA, k0cA, k1cA, bcA,
                    k0B, k1B, q0B, q1B, vvB, k0cB, k1cB, bcB,
                    S0, S1, sqp, cell, crow, l, iw, j);

    float* so = Sout + (((size_t)(b * HH + h)) * NNS + i) * NNS;
    so[l] = S0;
    so[l + 16] = S1;
}

extern "C" void kernel_launch(void* const* d_in, const int* in_sizes, int n_in,
                              void* d_out, int out_size, void* d_ws, size_t ws_size,
                              hipStream_t stream) {
    const float* x     = (const float*)d_in[0];
    const float* W_in  = (const float*)d_in[1];
    const float* W_k   = (const float*)d_in[2];
    const float* W_v   = (const float*)d_in[3];
    const float* W_q   = (const float*)d_in[4];
    const float* W_b   = (const float*)d_in[5];
    const float* b_b   = (const float*)d_in[6];
    const float* W_out = (const float*)d_in[7];
    float* out = (float*)d_out;

    const int M = MM;                                    // 16384
    float* f = (float*)d_ws;
    // region A: P fp32 [M,1024] — ALIASES Xh/Xl (dead before gemm2 writes P)
    float*  P    = f;
    ushort* Xh   = (ushort*)f;
    ushort* Xl   = Xh + (size_t)M * 1024;
    // region B: xp hi/lo planes [M,1024] each
    ushort* xpH  = (ushort*)(f + (size_t)M * 1024);
    ushort* xpL  = xpH + (size_t)M * 1024;
    // region C/D
    float*  KN   = f + (size_t)2 * M * 1024;             // M*256 fp32
    ushort* cell = (ushort*)(KN + (size_t)M * 256);      // M*256 bf16
    ushort* wb   = cell + (size_t)M * 256;               // weight planes
    ushort* W1h = wb;                    // 1M
    ushort* W1l = W1h + 1048576;         // 1M
    ushort* W2h = W1l + 1048576;         // 1M
    ushort* W2l = W2h + 1048576;         // 1M
    ushort* W3h = W2l + 1048576;         // 256K

    dim3 blk(256);
    dim3 g1(1024 / 128, M / 128);

    // 0) conversions (memory-bound pre-passes)
    conv_x_kernel<<<dim3((M * 1024) / (8 * 256)), blk, 0, stream>>>(x, Xh, Xl);
    conv_w_kernel<<<dim3(2359296 / (8 * 256)), blk, 0, stream>>>(
        W_in, W_k, W_v, W_q, W_b, W_out, W1h, W1l, W2h, W2l, W3h);
    // 1) xp = silu(x @ W_in^T), written directly as hi/lo planes
    gemm_planes<1><<<g1, blk, 0, stream>>>(Xh, Xl, W1h, W1l, b_b,
                                           xpH, xpL, nullptr, M, 1024, 1024);
    // 2) P = xp @ [Wk;Wv;Wq;Wbeta]^T, beta block: sigmoid(. + b_beta)
    gemm_planes<2><<<g1, blk, 0, stream>>>(xpH, xpL, W2h, W2l, b_b,
                                           nullptr, nullptr, P, M, 1024, 1024);
    // 3) kn = k / (||k|| + 1e-6)
    kn_kernel<<<dim3((M * 256) / 256), blk, 0, stream>>>(P, KN);
    // 4) recurrent scan -> cell (bf16) + S_final (fp32, d_out tail)
    scan_kernel<<<dim3(512), dim3(64), 0, stream>>>(P, KN, cell, out + (size_t)M * 1024);
    // 5) y = cell @ W_out^T
    gemm_cell<<<g1, blk, 0, stream>>>(cell, W3h, out, M, 1024, 256);
}